// Round 2
// baseline (585.471 us; speedup 1.0000x reference)
//
#include <hip/hip_runtime.h>

#define BATCH 65536
#define TB 64

typedef _Float16 half8 __attribute__((ext_vector_type(8)));
typedef float fx4 __attribute__((ext_vector_type(4)));

// workspace layout (in halves)
#define PW1_OFF 0        // [5][256][32]  phi_w1, K padded 146->160
#define PW2_OFF 40960    // [8][256][32]  phi_w2
#define PWR_OFF 106496   // [8][256][32]  rho_w1
#define PWH_OFF 172032   // [8][16][32]   [mean_w | lstd_w | zero-pad] N padded 8->16
#define WS_TOTAL 176128

__global__ __launch_bounds__(256) void prep_weights(
    const float* __restrict__ w1, const float* __restrict__ w2,
    const float* __restrict__ wr, const float* __restrict__ wm,
    const float* __restrict__ wl, _Float16* __restrict__ ws)
{
  int idx = blockIdx.x * 256 + threadIdx.x;
  if (idx < 40960) {
    int kk = idx & 31, n = (idx >> 5) & 255, kt = idx >> 13;
    int k = kt * 32 + kk;
    ws[idx] = (k < 146) ? (_Float16)w1[k * 256 + n] : (_Float16)0.f;
  } else if (idx < 106496) {
    int t = idx - 40960;
    int kk = t & 31, n = (t >> 5) & 255, kt = t >> 13;
    ws[idx] = (_Float16)w2[(kt * 32 + kk) * 256 + n];
  } else if (idx < 172032) {
    int t = idx - 106496;
    int kk = t & 31, n = (t >> 5) & 255, kt = t >> 13;
    ws[idx] = (_Float16)wr[(kt * 32 + kk) * 256 + n];
  } else if (idx < WS_TOTAL) {
    int t = idx - 172032;
    int kk = t & 31, n = (t >> 5) & 15, kt = t >> 9;
    int k = kt * 32 + kk;
    _Float16 v = (_Float16)0.f;
    if (n < 4) v = (_Float16)wm[k * 4 + n];
    else if (n < 8) v = (_Float16)wl[k * 4 + (n - 4)];
    ws[PWH_OFF + t] = v;
  }
}

// fragment-major LDS index: element (row, col) of a 64 x (KT*32) tile.
// a-fragment read for (m, kt, q, l16) is then base + (q*16+l16)*8 halves ->
// lane-contiguous 16B chunks -> conflict-free ds_read_b128.
__device__ __forceinline__ int afidx(int KT, int row, int col) {
  return ((((row >> 4) * KT + (col >> 5)) * 4 + ((col >> 3) & 3)) * 16 + (row & 15)) * 8 + (col & 7);
}

__global__ __launch_bounds__(256, 3) void actor_fused(
    const float* __restrict__ obs, const float* __restrict__ lemb,
    const _Float16* __restrict__ ws,
    const float* __restrict__ b1, const float* __restrict__ b2,
    const float* __restrict__ br, const float* __restrict__ bm,
    const float* __restrict__ bl, float* __restrict__ out)
{
  __shared__ __align__(16) _Float16 As[TB * 160]; // 20 KB, frag-major, KT=5
  __shared__ __align__(16) _Float16 Hs[TB * 256]; // 32 KB, frag-major, KT=8

  const _Float16* __restrict__ pw1 = ws + PW1_OFF;
  const _Float16* __restrict__ pw2 = ws + PW2_OFF;
  const _Float16* __restrict__ pwr = ws + PWR_OFF;
  const _Float16* __restrict__ pwh = ws + PWH_OFF;

  const int tid = threadIdx.x;
  const int wave = tid >> 6;
  const int lane = tid & 63;
  const int q = lane >> 4;
  const int l16 = lane & 15;
  const int colbase = wave * 64;
  const int rowbase = blockIdx.x * TB;

  // ---- one-time staging: l_emb -> cols 0..99, body -> cols 100..109, pad 146..159 ----
  for (int idx = tid; idx < TB * 100; idx += 256) {
    int r = idx / 100, c = idx - r * 100;
    As[afidx(5, r, c)] = (_Float16)lemb[(rowbase + r) * 100 + c];
  }
  for (int idx = tid; idx < TB * 10; idx += 256) {
    int r = idx / 10, c = idx - r * 10;
    As[afidx(5, r, 100 + c)] = (_Float16)obs[(rowbase + r) * 55 + c];
  }
  for (int idx = tid; idx < TB * 14; idx += 256) {
    int r = idx / 14, c = idx - r * 14;
    As[afidx(5, r, 146 + c)] = (_Float16)0.f;
  }

  const fx4 zero4 = {0.f, 0.f, 0.f, 0.f};
  fx4 agg[16];
  #pragma unroll
  for (int i = 0; i < 16; ++i) agg[i] = zero4;

  for (int p = 0; p < 6; ++p) {
    const int oi = p >> 1;
    const int oj = (1161 >> (2 * p)) & 3; // {1,2,0,2,0,1}

    // ---- build object cols 110..145 ----
    for (int idx = tid; idx < TB * 36; idx += 256) {
      int r = idx / 36, c = idx - r * 36;
      float v;
      if (c < 3)       v = (c == oi) ? 1.f : 0.f;
      else if (c < 18) v = obs[(rowbase + r) * 55 + 10 + oi * 15 + (c - 3)];
      else if (c < 21) v = ((c - 18) == oj) ? 1.f : 0.f;
      else             v = obs[(rowbase + r) * 55 + 10 + oj * 15 + (c - 21)];
      As[afidx(5, r, 110 + c)] = (_Float16)v;
    }
    __syncthreads();

    // ---- GEMM1: h1 = relu(A @ W1 + b1), K=160, N split in two 32-col halves ----
    #pragma unroll
    for (int half = 0; half < 2; ++half) {
      fx4 acc[8];
      #pragma unroll
      for (int i = 0; i < 8; ++i) acc[i] = zero4;
      for (int kt = 0; kt < 5; ++kt) {
        half8 a[4], b[2];
        #pragma unroll
        for (int m = 0; m < 4; ++m)
          a[m] = *(const half8*)&As[(((m * 5 + kt) * 4 + q) * 16 + l16) * 8];
        #pragma unroll
        for (int n = 0; n < 2; ++n)
          b[n] = *(const half8*)&pw1[(kt * 256 + colbase + half * 32 + n * 16 + l16) * 32 + q * 8];
        #pragma unroll
        for (int m = 0; m < 4; ++m)
          #pragma unroll
          for (int n = 0; n < 2; ++n)
            acc[m * 2 + n] = __builtin_amdgcn_mfma_f32_16x16x32_f16(a[m], b[n], acc[m * 2 + n], 0, 0, 0);
      }
      #pragma unroll
      for (int n = 0; n < 2; ++n) {
        int col = colbase + half * 32 + n * 16 + l16;
        float bias = b1[col];
        int ktc = col >> 5;            // = wave*2 + half
        int q2 = 2 * n + (l16 >> 3);
        int j = l16 & 7;
        #pragma unroll
        for (int m = 0; m < 4; ++m)
          #pragma unroll
          for (int rr = 0; rr < 4; ++rr) {
            float h = acc[m * 2 + n][rr] + bias;
            Hs[(((m * 8 + ktc) * 4 + q2) * 16 + (4 * q + rr)) * 8 + j] = (_Float16)(h > 0.f ? h : 0.f);
          }
      }
    }
    __syncthreads();

    // ---- GEMM2: agg += relu(h1 @ W2 + b2), K=256, N split in halves ----
    #pragma unroll
    for (int half = 0; half < 2; ++half) {
      fx4 acc[8];
      #pragma unroll
      for (int i = 0; i < 8; ++i) acc[i] = zero4;
      for (int kt = 0; kt < 8; ++kt) {
        half8 a[4], b[2];
        #pragma unroll
        for (int m = 0; m < 4; ++m)
          a[m] = *(const half8*)&Hs[(((m * 8 + kt) * 4 + q) * 16 + l16) * 8];
        #pragma unroll
        for (int n = 0; n < 2; ++n)
          b[n] = *(const half8*)&pw2[(kt * 256 + colbase + half * 32 + n * 16 + l16) * 32 + q * 8];
        #pragma unroll
        for (int m = 0; m < 4; ++m)
          #pragma unroll
          for (int n = 0; n < 2; ++n)
            acc[m * 2 + n] = __builtin_amdgcn_mfma_f32_16x16x32_f16(a[m], b[n], acc[m * 2 + n], 0, 0, 0);
      }
      #pragma unroll
      for (int n = 0; n < 2; ++n) {
        float bias = b2[colbase + half * 32 + n * 16 + l16];
        #pragma unroll
        for (int m = 0; m < 4; ++m)
          #pragma unroll
          for (int rr = 0; rr < 4; ++rr) {
            float h = acc[m * 2 + n][rr] + bias;
            if (h > 0.f) agg[m * 4 + half * 2 + n][rr] += h;
          }
      }
    }
    __syncthreads();  // next perm's build writes As / GEMM1 writes Hs
  }

  // ---- stage agg into Hs (f16) ----
  #pragma unroll
  for (int jn = 0; jn < 4; ++jn) {
    int col = colbase + jn * 16 + l16;
    int ktc = col >> 5;
    int q2 = 2 * (jn & 1) + (l16 >> 3);
    int j = l16 & 7;
    #pragma unroll
    for (int m = 0; m < 4; ++m)
      #pragma unroll
      for (int rr = 0; rr < 4; ++rr)
        Hs[(((m * 8 + ktc) * 4 + q2) * 16 + (4 * q + rr)) * 8 + j] = (_Float16)agg[m * 4 + jn][rr];
  }
  __syncthreads();

  // ---- GEMM3: r = relu(agg @ rho_w1 + rho_b1), K=256, full N (agg regs dead) ----
  fx4 acc3[16];
  #pragma unroll
  for (int i = 0; i < 16; ++i) acc3[i] = zero4;
  for (int kt = 0; kt < 8; ++kt) {
    half8 a[4], b[4];
    #pragma unroll
    for (int m = 0; m < 4; ++m)
      a[m] = *(const half8*)&Hs[(((m * 8 + kt) * 4 + q) * 16 + l16) * 8];
    #pragma unroll
    for (int n = 0; n < 4; ++n)
      b[n] = *(const half8*)&pwr[(kt * 256 + colbase + n * 16 + l16) * 32 + q * 8];
    #pragma unroll
    for (int m = 0; m < 4; ++m)
      #pragma unroll
      for (int n = 0; n < 4; ++n)
        acc3[m * 4 + n] = __builtin_amdgcn_mfma_f32_16x16x32_f16(a[m], b[n], acc3[m * 4 + n], 0, 0, 0);
  }
  __syncthreads();  // all reads of Hs done before overwrite
  #pragma unroll
  for (int n = 0; n < 4; ++n) {
    int col = colbase + n * 16 + l16;
    float bias = br[col];
    int ktc = col >> 5;
    int q2 = 2 * (n & 1) + (l16 >> 3);
    int j = l16 & 7;
    #pragma unroll
    for (int m = 0; m < 4; ++m)
      #pragma unroll
      for (int rr = 0; rr < 4; ++rr) {
        float h = acc3[m * 4 + n][rr] + bias;
        Hs[(((m * 8 + ktc) * 4 + q2) * 16 + (4 * q + rr)) * 8 + j] = (_Float16)(h > 0.f ? h : 0.f);
      }
  }
  __syncthreads();

  // ---- heads: [mean | log_std] = r @ PWh (N padded to 16), wave w does rows w*16..w*16+15 ----
  fx4 a4 = zero4;
  for (int kt = 0; kt < 8; ++kt) {
    half8 a = *(const half8*)&Hs[(((wave * 8 + kt) * 4 + q) * 16 + l16) * 8];
    half8 b = *(const half8*)&pwh[(kt * 16 + l16) * 32 + q * 8];
    a4 = __builtin_amdgcn_mfma_f32_16x16x32_f16(a, b, a4, 0, 0, 0);
  }
  int gr = rowbase + wave * 16 + q * 4;
  if (l16 < 4) {
    float bias = bm[l16];
    #pragma unroll
    for (int rr = 0; rr < 4; ++rr) out[(gr + rr) * 4 + l16] = a4[rr] + bias;
  } else if (l16 < 8) {
    int c = l16 - 4;
    float bias = bl[c];
    #pragma unroll
    for (int rr = 0; rr < 4; ++rr) {
      float v = a4[rr] + bias;
      v = v < -20.f ? -20.f : (v > 2.f ? 2.f : v);
      out[BATCH * 4 + (gr + rr) * 4 + c] = v;
    }
  }
}

extern "C" void kernel_launch(void* const* d_in, const int* in_sizes, int n_in,
                              void* d_out, int out_size, void* d_ws, size_t ws_size,
                              hipStream_t stream) {
  const float* obs  = (const float*)d_in[0];
  const float* lemb = (const float*)d_in[1];
  const float* w1   = (const float*)d_in[2];
  const float* b1   = (const float*)d_in[3];
  const float* w2   = (const float*)d_in[4];
  const float* b2   = (const float*)d_in[5];
  const float* wr   = (const float*)d_in[6];
  const float* br   = (const float*)d_in[7];
  const float* wm   = (const float*)d_in[8];
  const float* bm   = (const float*)d_in[9];
  const float* wl   = (const float*)d_in[10];
  const float* bl   = (const float*)d_in[11];
  float* out = (float*)d_out;
  _Float16* ws = (_Float16*)d_ws;

  hipLaunchKernelGGL(prep_weights, dim3((WS_TOTAL + 255) / 256), dim3(256), 0, stream,
                     w1, w2, wr, wm, wl, ws);
  hipLaunchKernelGGL(actor_fused, dim3(BATCH / TB), dim3(256), 0, stream,
                     obs, lemb, (const _Float16*)ws, b1, b2, br, bm, bl, out);
}

// Round 3
// 389.776 us; speedup vs baseline: 1.5021x; 1.5021x over previous
//
#include <hip/hip_runtime.h>

#define BATCH 65536
#define TB 64

typedef _Float16 half8 __attribute__((ext_vector_type(8)));
typedef float fx4 __attribute__((ext_vector_type(4)));

// workspace layout (in halves)
#define PW1_OFF 0        // [5][256][32]  phi_w1, K padded 146->160
#define PW2_OFF 40960    // [8][256][32]  phi_w2
#define PWR_OFF 106496   // [8][256][32]  rho_w1
#define PWH_OFF 172032   // [8][16][32]   [mean_w | lstd_w | zero-pad] N padded 8->16
#define WS_TOTAL 176128

__global__ __launch_bounds__(256) void prep_weights(
    const float* __restrict__ w1, const float* __restrict__ w2,
    const float* __restrict__ wr, const float* __restrict__ wm,
    const float* __restrict__ wl, _Float16* __restrict__ ws)
{
  int idx = blockIdx.x * 256 + threadIdx.x;
  if (idx < 40960) {
    int kk = idx & 31, n = (idx >> 5) & 255, kt = idx >> 13;
    int k = kt * 32 + kk;
    ws[idx] = (k < 146) ? (_Float16)w1[k * 256 + n] : (_Float16)0.f;
  } else if (idx < 106496) {
    int t = idx - 40960;
    int kk = t & 31, n = (t >> 5) & 255, kt = t >> 13;
    ws[idx] = (_Float16)w2[(kt * 32 + kk) * 256 + n];
  } else if (idx < 172032) {
    int t = idx - 106496;
    int kk = t & 31, n = (t >> 5) & 255, kt = t >> 13;
    ws[idx] = (_Float16)wr[(kt * 32 + kk) * 256 + n];
  } else if (idx < WS_TOTAL) {
    int t = idx - 172032;
    int kk = t & 31, n = (t >> 5) & 15, kt = t >> 9;
    int k = kt * 32 + kk;
    _Float16 v = (_Float16)0.f;
    if (n < 4) v = (_Float16)wm[k * 4 + n];
    else if (n < 8) v = (_Float16)wl[k * 4 + (n - 4)];
    ws[PWH_OFF + t] = v;
  }
}

// fragment-major LDS index: element (row, col) of a 64 x (KT*32) tile.
// a-fragment read for (m, kt, q, l16) is then lane-contiguous 16B chunks
// -> conflict-free ds_read_b128.
__device__ __forceinline__ int afidx(int KT, int row, int col) {
  return ((((row >> 4) * KT + (col >> 5)) * 4 + ((col >> 3) & 3)) * 16 + (row & 15)) * 8 + (col & 7);
}

// launch_bounds(256,2): 256 regs/wave budget. Live set ~190 (agg 64 AGPR +
// acc 32 AGPR + frags 24 + addr) -> no spill. (256,3)'s 170 budget spilled
// ~1.1 GB of scratch in R2; (256,2) trades occupancy (2 blk/CU) for zero spill.
__global__ __launch_bounds__(256, 2) void actor_fused(
    const float* __restrict__ obs, const float* __restrict__ lemb,
    const _Float16* __restrict__ ws,
    const float* __restrict__ b1, const float* __restrict__ b2,
    const float* __restrict__ br, const float* __restrict__ bm,
    const float* __restrict__ bl, float* __restrict__ out)
{
  __shared__ __align__(16) _Float16 As[TB * 160]; // 20 KB, frag-major, KT=5
  __shared__ __align__(16) _Float16 Hs[TB * 256]; // 32 KB, frag-major, KT=8
  __shared__ _Float16 Fs[TB * 45];                // 5.6 KB object features

  const _Float16* __restrict__ pw1 = ws + PW1_OFF;
  const _Float16* __restrict__ pw2 = ws + PW2_OFF;
  const _Float16* __restrict__ pwr = ws + PWR_OFF;
  const _Float16* __restrict__ pwh = ws + PWH_OFF;

  const int tid = threadIdx.x;
  const int wave = tid >> 6;
  const int lane = tid & 63;
  const int q = lane >> 4;
  const int l16 = lane & 15;
  const int colbase = wave * 64;
  const int rowbase = blockIdx.x * TB;

  // ---- one-time staging: l_emb -> cols 0..99, body -> 100..109, feats -> Fs ----
  for (int idx = tid; idx < TB * 100; idx += 256) {
    int r = idx / 100, c = idx - r * 100;
    As[afidx(5, r, c)] = (_Float16)lemb[(rowbase + r) * 100 + c];
  }
  for (int idx = tid; idx < TB * 55; idx += 256) {
    int r = idx / 55, c = idx - r * 55;
    float v = obs[(rowbase + r) * 55 + c];
    if (c < 10) As[afidx(5, r, 100 + c)] = (_Float16)v;
    else Fs[r * 45 + (c - 10)] = (_Float16)v;
  }
  for (int idx = tid; idx < TB * 14; idx += 256) {
    int r = idx / 14, c = idx - r * 14;
    As[afidx(5, r, 146 + c)] = (_Float16)0.f;
  }

  const fx4 zero4 = {0.f, 0.f, 0.f, 0.f};
  fx4 agg[16];
  #pragma unroll
  for (int i = 0; i < 16; ++i) agg[i] = zero4;

  for (int p = 0; p < 6; ++p) {
    const int oi = p >> 1;
    const int oj = (1161 >> (2 * p)) & 3; // {1,2,0,2,0,1}

    // ---- build object cols 110..145 from Fs ----
    for (int idx = tid; idx < TB * 36; idx += 256) {
      int r = idx / 36, c = idx - r * 36;
      _Float16 v;
      if (c < 3)       v = (_Float16)((c == oi) ? 1.f : 0.f);
      else if (c < 18) v = Fs[r * 45 + oi * 15 + (c - 3)];
      else if (c < 21) v = (_Float16)(((c - 18) == oj) ? 1.f : 0.f);
      else             v = Fs[r * 45 + oj * 15 + (c - 21)];
      As[afidx(5, r, 110 + c)] = v;
    }
    __syncthreads();

    // ---- GEMM1: h1 = relu(A @ W1 + b1), K=160, N in two 32-col halves ----
    #pragma unroll
    for (int half = 0; half < 2; ++half) {
      fx4 acc[8];
      #pragma unroll
      for (int i = 0; i < 8; ++i) acc[i] = zero4;
      for (int kt = 0; kt < 5; ++kt) {
        half8 a[4], b[2];
        #pragma unroll
        for (int m = 0; m < 4; ++m)
          a[m] = *(const half8*)&As[(((m * 5 + kt) * 4 + q) * 16 + l16) * 8];
        #pragma unroll
        for (int n = 0; n < 2; ++n)
          b[n] = *(const half8*)&pw1[(kt * 256 + colbase + half * 32 + n * 16 + l16) * 32 + q * 8];
        #pragma unroll
        for (int m = 0; m < 4; ++m)
          #pragma unroll
          for (int n = 0; n < 2; ++n)
            acc[m * 2 + n] = __builtin_amdgcn_mfma_f32_16x16x32_f16(a[m], b[n], acc[m * 2 + n], 0, 0, 0);
      }
      #pragma unroll
      for (int n = 0; n < 2; ++n) {
        int col = colbase + half * 32 + n * 16 + l16;
        float bias = b1[col];
        int ktc = col >> 5;            // = wave*2 + half
        int q2 = 2 * n + (l16 >> 3);
        int j = l16 & 7;
        #pragma unroll
        for (int m = 0; m < 4; ++m)
          #pragma unroll
          for (int rr = 0; rr < 4; ++rr) {
            float h = acc[m * 2 + n][rr] + bias;
            Hs[(((m * 8 + ktc) * 4 + q2) * 16 + (4 * q + rr)) * 8 + j] = (_Float16)(h > 0.f ? h : 0.f);
          }
      }
    }
    __syncthreads();

    // ---- GEMM2: agg += relu(h1 @ W2 + b2), K=256, N in halves ----
    #pragma unroll
    for (int half = 0; half < 2; ++half) {
      fx4 acc[8];
      #pragma unroll
      for (int i = 0; i < 8; ++i) acc[i] = zero4;
      for (int kt = 0; kt < 8; ++kt) {
        half8 a[4], b[2];
        #pragma unroll
        for (int m = 0; m < 4; ++m)
          a[m] = *(const half8*)&Hs[(((m * 8 + kt) * 4 + q) * 16 + l16) * 8];
        #pragma unroll
        for (int n = 0; n < 2; ++n)
          b[n] = *(const half8*)&pw2[(kt * 256 + colbase + half * 32 + n * 16 + l16) * 32 + q * 8];
        #pragma unroll
        for (int m = 0; m < 4; ++m)
          #pragma unroll
          for (int n = 0; n < 2; ++n)
            acc[m * 2 + n] = __builtin_amdgcn_mfma_f32_16x16x32_f16(a[m], b[n], acc[m * 2 + n], 0, 0, 0);
      }
      #pragma unroll
      for (int n = 0; n < 2; ++n) {
        float bias = b2[colbase + half * 32 + n * 16 + l16];
        #pragma unroll
        for (int m = 0; m < 4; ++m)
          #pragma unroll
          for (int rr = 0; rr < 4; ++rr) {
            float h = acc[m * 2 + n][rr] + bias;
            if (h > 0.f) agg[m * 4 + half * 2 + n][rr] += h;
          }
      }
    }
    __syncthreads();  // Hs reads done before next perm's GEMM1 overwrites; As build safe
  }

  // ---- stage agg into Hs (f16) ----
  #pragma unroll
  for (int jn = 0; jn < 4; ++jn) {
    int col = colbase + jn * 16 + l16;
    int ktc = col >> 5;
    int q2 = 2 * (jn & 1) + (l16 >> 3);
    int j = l16 & 7;
    #pragma unroll
    for (int m = 0; m < 4; ++m)
      #pragma unroll
      for (int rr = 0; rr < 4; ++rr)
        Hs[(((m * 8 + ktc) * 4 + q2) * 16 + (4 * q + rr)) * 8 + j] = (_Float16)agg[m * 4 + jn][rr];
  }
  __syncthreads();

  // ---- GEMM3: r = relu(agg @ rho_w1 + rho_b1), K=256, full N (agg dead) ----
  fx4 acc3[16];
  #pragma unroll
  for (int i = 0; i < 16; ++i) acc3[i] = zero4;
  for (int kt = 0; kt < 8; ++kt) {
    half8 a[4], b[4];
    #pragma unroll
    for (int m = 0; m < 4; ++m)
      a[m] = *(const half8*)&Hs[(((m * 8 + kt) * 4 + q) * 16 + l16) * 8];
    #pragma unroll
    for (int n = 0; n < 4; ++n)
      b[n] = *(const half8*)&pwr[(kt * 256 + colbase + n * 16 + l16) * 32 + q * 8];
    #pragma unroll
    for (int m = 0; m < 4; ++m)
      #pragma unroll
      for (int n = 0; n < 4; ++n)
        acc3[m * 4 + n] = __builtin_amdgcn_mfma_f32_16x16x32_f16(a[m], b[n], acc3[m * 4 + n], 0, 0, 0);
  }
  __syncthreads();  // all reads of Hs done before overwrite
  #pragma unroll
  for (int n = 0; n < 4; ++n) {
    int col = colbase + n * 16 + l16;
    float bias = br[col];
    int ktc = col >> 5;
    int q2 = 2 * (n & 1) + (l16 >> 3);
    int j = l16 & 7;
    #pragma unroll
    for (int m = 0; m < 4; ++m)
      #pragma unroll
      for (int rr = 0; rr < 4; ++rr) {
        float h = acc3[m * 4 + n][rr] + bias;
        Hs[(((m * 8 + ktc) * 4 + q2) * 16 + (4 * q + rr)) * 8 + j] = (_Float16)(h > 0.f ? h : 0.f);
      }
  }
  __syncthreads();

  // ---- heads: [mean | log_std] = r @ PWh (N padded to 16) ----
  fx4 a4 = zero4;
  for (int kt = 0; kt < 8; ++kt) {
    half8 a = *(const half8*)&Hs[(((wave * 8 + kt) * 4 + q) * 16 + l16) * 8];
    half8 b = *(const half8*)&pwh[(kt * 16 + l16) * 32 + q * 8];
    a4 = __builtin_amdgcn_mfma_f32_16x16x32_f16(a, b, a4, 0, 0, 0);
  }
  int gr = rowbase + wave * 16 + q * 4;
  if (l16 < 4) {
    float bias = bm[l16];
    #pragma unroll
    for (int rr = 0; rr < 4; ++rr) out[(gr + rr) * 4 + l16] = a4[rr] + bias;
  } else if (l16 < 8) {
    int c = l16 - 4;
    float bias = bl[c];
    #pragma unroll
    for (int rr = 0; rr < 4; ++rr) {
      float v = a4[rr] + bias;
      v = v < -20.f ? -20.f : (v > 2.f ? 2.f : v);
      out[BATCH * 4 + (gr + rr) * 4 + c] = v;
    }
  }
}

extern "C" void kernel_launch(void* const* d_in, const int* in_sizes, int n_in,
                              void* d_out, int out_size, void* d_ws, size_t ws_size,
                              hipStream_t stream) {
  const float* obs  = (const float*)d_in[0];
  const float* lemb = (const float*)d_in[1];
  const float* w1   = (const float*)d_in[2];
  const float* b1   = (const float*)d_in[3];
  const float* w2   = (const float*)d_in[4];
  const float* b2   = (const float*)d_in[5];
  const float* wr   = (const float*)d_in[6];
  const float* br   = (const float*)d_in[7];
  const float* wm   = (const float*)d_in[8];
  const float* bm   = (const float*)d_in[9];
  const float* wl   = (const float*)d_in[10];
  const float* bl   = (const float*)d_in[11];
  float* out = (float*)d_out;
  _Float16* ws = (_Float16*)d_ws;

  hipLaunchKernelGGL(prep_weights, dim3((WS_TOTAL + 255) / 256), dim3(256), 0, stream,
                     w1, w2, wr, wm, wl, ws);
  hipLaunchKernelGGL(actor_fused, dim3(BATCH / TB), dim3(256), 0, stream,
                     obs, lemb, (const _Float16*)ws, b1, b2, br, bm, bl, out);
}

// Round 4
// 351.502 us; speedup vs baseline: 1.6656x; 1.1089x over previous
//
#include <hip/hip_runtime.h>

#define BATCH 65536
#define TB 64

typedef _Float16 half8 __attribute__((ext_vector_type(8)));
typedef _Float16 half2v __attribute__((ext_vector_type(2)));
typedef float fx4 __attribute__((ext_vector_type(4)));

// workspace layout (in halves)
#define PW1_OFF 0        // [5][256][32]  phi_w1, K padded 146->160
#define PW2_OFF 40960    // [8][256][32]  phi_w2
#define PWR_OFF 106496   // [8][256][32]  rho_w1
#define PWH_OFF 172032   // [8][16][32]   [mean_w | lstd_w | zero-pad] N padded 8->16
#define WS_TOTAL 176128

__global__ __launch_bounds__(256) void prep_weights(
    const float* __restrict__ w1, const float* __restrict__ w2,
    const float* __restrict__ wr, const float* __restrict__ wm,
    const float* __restrict__ wl, _Float16* __restrict__ ws)
{
  int idx = blockIdx.x * 256 + threadIdx.x;
  if (idx < 40960) {
    int kk = idx & 31, n = (idx >> 5) & 255, kt = idx >> 13;
    int k = kt * 32 + kk;
    ws[idx] = (k < 146) ? (_Float16)w1[k * 256 + n] : (_Float16)0.f;
  } else if (idx < 106496) {
    int t = idx - 40960;
    int kk = t & 31, n = (t >> 5) & 255, kt = t >> 13;
    ws[idx] = (_Float16)w2[(kt * 32 + kk) * 256 + n];
  } else if (idx < 172032) {
    int t = idx - 106496;
    int kk = t & 31, n = (t >> 5) & 255, kt = t >> 13;
    ws[idx] = (_Float16)wr[(kt * 32 + kk) * 256 + n];
  } else if (idx < WS_TOTAL) {
    int t = idx - 172032;
    int kk = t & 31, n = (t >> 5) & 15, kt = t >> 9;
    int k = kt * 32 + kk;
    _Float16 v = (_Float16)0.f;
    if (n < 4) v = (_Float16)wm[k * 4 + n];
    else if (n < 8) v = (_Float16)wl[k * 4 + (n - 4)];
    ws[PWH_OFF + t] = v;
  }
}

// fragment-major LDS index: element (row, col) of a 64 x (KT*32) tile.
// a-fragment read for (m, kt, q, l16) is lane-contiguous 16B -> conflict-free ds_read_b128.
__device__ __forceinline__ int afidx(int KT, int row, int col) {
  return ((((row >> 4) * KT + (col >> 5)) * 4 + ((col >> 3) & 3)) * 16 + (row & 15)) * 8 + (col & 7);
}

// Register budget is the whole game (R1-R3 post-mortems): at (256,2) the
// allocator gives ~128 arch VGPRs; agg as fp32 (64 regs) + acc (32) + frags
// overflowed it -> ~400 MB/dispatch scratch round-trip. agg as packed-f16
// pairs (32 regs, v_pk_add_f16) brings peak live set to ~115 regs -> no spill.
// f16 agg costs nothing numerically: it feeds GEMM3 as an f16 MFMA operand anyway.
__global__ __launch_bounds__(256, 2) void actor_fused(
    const float* __restrict__ obs, const float* __restrict__ lemb,
    const _Float16* __restrict__ ws,
    const float* __restrict__ b1, const float* __restrict__ b2,
    const float* __restrict__ br, const float* __restrict__ bm,
    const float* __restrict__ bl, float* __restrict__ out)
{
  __shared__ __align__(16) _Float16 As[TB * 160]; // 20 KB, frag-major, KT=5
  __shared__ __align__(16) _Float16 Hs[TB * 256]; // 32 KB, frag-major, KT=8
  __shared__ _Float16 Fs[TB * 45];                // 5.6 KB object features

  const _Float16* __restrict__ pw1 = ws + PW1_OFF;
  const _Float16* __restrict__ pw2 = ws + PW2_OFF;
  const _Float16* __restrict__ pwr = ws + PWR_OFF;
  const _Float16* __restrict__ pwh = ws + PWH_OFF;

  const int tid = threadIdx.x;
  const int wave = tid >> 6;
  const int lane = tid & 63;
  const int q = lane >> 4;
  const int l16 = lane & 15;
  const int colbase = wave * 64;
  const int rowbase = blockIdx.x * TB;

  // ---- one-time staging: l_emb -> cols 0..99, body -> 100..109, feats -> Fs ----
  for (int idx = tid; idx < TB * 100; idx += 256) {
    int r = idx / 100, c = idx - r * 100;
    As[afidx(5, r, c)] = (_Float16)lemb[(rowbase + r) * 100 + c];
  }
  for (int idx = tid; idx < TB * 55; idx += 256) {
    int r = idx / 55, c = idx - r * 55;
    float v = obs[(rowbase + r) * 55 + c];
    if (c < 10) As[afidx(5, r, 100 + c)] = (_Float16)v;
    else Fs[r * 45 + (c - 10)] = (_Float16)v;
  }
  for (int idx = tid; idx < TB * 14; idx += 256) {
    int r = idx / 14, c = idx - r * 14;
    As[afidx(5, r, 146 + c)] = (_Float16)0.f;
  }

  const fx4 zero4 = {0.f, 0.f, 0.f, 0.f};
  // agg as packed f16: slot (m*4+jn) holds rows (m*16+q*4+rr), col (colbase+jn*16+l16);
  // pair index rp = rr>>1, element rr&1.
  half2v agg2[32];
  #pragma unroll
  for (int i = 0; i < 32; ++i) agg2[i] = (half2v)0;

  for (int p = 0; p < 6; ++p) {
    const int oi = p >> 1;
    const int oj = (1161 >> (2 * p)) & 3; // {1,2,0,2,0,1}

    // ---- build object cols 110..145 from Fs ----
    for (int idx = tid; idx < TB * 36; idx += 256) {
      int r = idx / 36, c = idx - r * 36;
      _Float16 v;
      if (c < 3)       v = (_Float16)((c == oi) ? 1.f : 0.f);
      else if (c < 18) v = Fs[r * 45 + oi * 15 + (c - 3)];
      else if (c < 21) v = (_Float16)(((c - 18) == oj) ? 1.f : 0.f);
      else             v = Fs[r * 45 + oj * 15 + (c - 21)];
      As[afidx(5, r, 110 + c)] = v;
    }
    __syncthreads();

    // ---- GEMM1: h1 = relu(A @ W1 + b1), K=160, N in two 32-col halves ----
    #pragma unroll
    for (int half = 0; half < 2; ++half) {
      fx4 acc[8];
      #pragma unroll
      for (int i = 0; i < 8; ++i) acc[i] = zero4;
      for (int kt = 0; kt < 5; ++kt) {
        half8 a[4], b[2];
        #pragma unroll
        for (int m = 0; m < 4; ++m)
          a[m] = *(const half8*)&As[(((m * 5 + kt) * 4 + q) * 16 + l16) * 8];
        #pragma unroll
        for (int n = 0; n < 2; ++n)
          b[n] = *(const half8*)&pw1[(kt * 256 + colbase + half * 32 + n * 16 + l16) * 32 + q * 8];
        #pragma unroll
        for (int m = 0; m < 4; ++m)
          #pragma unroll
          for (int n = 0; n < 2; ++n)
            acc[m * 2 + n] = __builtin_amdgcn_mfma_f32_16x16x32_f16(a[m], b[n], acc[m * 2 + n], 0, 0, 0);
      }
      #pragma unroll
      for (int n = 0; n < 2; ++n) {
        int col = colbase + half * 32 + n * 16 + l16;
        float bias = b1[col];
        int ktc = col >> 5;            // = wave*2 + half
        int q2 = 2 * n + (l16 >> 3);
        int j = l16 & 7;
        #pragma unroll
        for (int m = 0; m < 4; ++m)
          #pragma unroll
          for (int rr = 0; rr < 4; ++rr) {
            float h = acc[m * 2 + n][rr] + bias;
            Hs[(((m * 8 + ktc) * 4 + q2) * 16 + (4 * q + rr)) * 8 + j] = (_Float16)(h > 0.f ? h : 0.f);
          }
      }
    }
    __syncthreads();

    // ---- GEMM2: agg += relu(h1 @ W2 + b2), K=256, N in halves ----
    #pragma unroll
    for (int half = 0; half < 2; ++half) {
      fx4 acc[8];
      #pragma unroll
      for (int i = 0; i < 8; ++i) acc[i] = zero4;
      for (int kt = 0; kt < 8; ++kt) {
        half8 a[4], b[2];
        #pragma unroll
        for (int m = 0; m < 4; ++m)
          a[m] = *(const half8*)&Hs[(((m * 8 + kt) * 4 + q) * 16 + l16) * 8];
        #pragma unroll
        for (int n = 0; n < 2; ++n)
          b[n] = *(const half8*)&pw2[(kt * 256 + colbase + half * 32 + n * 16 + l16) * 32 + q * 8];
        #pragma unroll
        for (int m = 0; m < 4; ++m)
          #pragma unroll
          for (int n = 0; n < 2; ++n)
            acc[m * 2 + n] = __builtin_amdgcn_mfma_f32_16x16x32_f16(a[m], b[n], acc[m * 2 + n], 0, 0, 0);
      }
      #pragma unroll
      for (int n = 0; n < 2; ++n) {
        int jn = half * 2 + n;
        float bias = b2[colbase + jn * 16 + l16];
        #pragma unroll
        for (int m = 0; m < 4; ++m)
          #pragma unroll
          for (int rp = 0; rp < 2; ++rp) {
            float h0 = acc[m * 2 + n][rp * 2 + 0] + bias;
            float h1 = acc[m * 2 + n][rp * 2 + 1] + bias;
            half2v hv;
            hv[0] = (_Float16)(h0 > 0.f ? h0 : 0.f);
            hv[1] = (_Float16)(h1 > 0.f ? h1 : 0.f);
            agg2[(m * 4 + jn) * 2 + rp] += hv;   // v_pk_add_f16
          }
      }
    }
    __syncthreads();  // Hs reads done before next perm's GEMM1; As build safe
  }

  // ---- stage agg into Hs (already f16) ----
  #pragma unroll
  for (int jn = 0; jn < 4; ++jn) {
    int col = colbase + jn * 16 + l16;
    int ktc = col >> 5;
    int q2 = 2 * (jn & 1) + (l16 >> 3);
    int j = l16 & 7;
    #pragma unroll
    for (int m = 0; m < 4; ++m)
      #pragma unroll
      for (int rr = 0; rr < 4; ++rr)
        Hs[(((m * 8 + ktc) * 4 + q2) * 16 + (4 * q + rr)) * 8 + j] = agg2[(m * 4 + jn) * 2 + (rr >> 1)][rr & 1];
  }
  __syncthreads();

  // ---- GEMM3: r = relu(agg @ rho_w1 + rho_b1), K=256, full N (agg2 dead) ----
  fx4 acc3[16];
  #pragma unroll
  for (int i = 0; i < 16; ++i) acc3[i] = zero4;
  for (int kt = 0; kt < 8; ++kt) {
    half8 a[4], b[4];
    #pragma unroll
    for (int m = 0; m < 4; ++m)
      a[m] = *(const half8*)&Hs[(((m * 8 + kt) * 4 + q) * 16 + l16) * 8];
    #pragma unroll
    for (int n = 0; n < 4; ++n)
      b[n] = *(const half8*)&pwr[(kt * 256 + colbase + n * 16 + l16) * 32 + q * 8];
    #pragma unroll
    for (int m = 0; m < 4; ++m)
      #pragma unroll
      for (int n = 0; n < 4; ++n)
        acc3[m * 4 + n] = __builtin_amdgcn_mfma_f32_16x16x32_f16(a[m], b[n], acc3[m * 4 + n], 0, 0, 0);
  }
  __syncthreads();  // all reads of Hs done before overwrite
  #pragma unroll
  for (int n = 0; n < 4; ++n) {
    int col = colbase + n * 16 + l16;
    float bias = br[col];
    int ktc = col >> 5;
    int q2 = 2 * (n & 1) + (l16 >> 3);
    int j = l16 & 7;
    #pragma unroll
    for (int m = 0; m < 4; ++m)
      #pragma unroll
      for (int rr = 0; rr < 4; ++rr) {
        float h = acc3[m * 4 + n][rr] + bias;
        Hs[(((m * 8 + ktc) * 4 + q2) * 16 + (4 * q + rr)) * 8 + j] = (_Float16)(h > 0.f ? h : 0.f);
      }
  }
  __syncthreads();

  // ---- heads: [mean | log_std] = r @ PWh (N padded to 16) ----
  fx4 a4 = zero4;
  for (int kt = 0; kt < 8; ++kt) {
    half8 a = *(const half8*)&Hs[(((wave * 8 + kt) * 4 + q) * 16 + l16) * 8];
    half8 b = *(const half8*)&pwh[(kt * 16 + l16) * 32 + q * 8];
    a4 = __builtin_amdgcn_mfma_f32_16x16x32_f16(a, b, a4, 0, 0, 0);
  }
  int gr = rowbase + wave * 16 + q * 4;
  if (l16 < 4) {
    float bias = bm[l16];
    #pragma unroll
    for (int rr = 0; rr < 4; ++rr) out[(gr + rr) * 4 + l16] = a4[rr] + bias;
  } else if (l16 < 8) {
    int c = l16 - 4;
    float bias = bl[c];
    #pragma unroll
    for (int rr = 0; rr < 4; ++rr) {
      float v = a4[rr] + bias;
      v = v < -20.f ? -20.f : (v > 2.f ? 2.f : v);
      out[BATCH * 4 + (gr + rr) * 4 + c] = v;
    }
  }
}

extern "C" void kernel_launch(void* const* d_in, const int* in_sizes, int n_in,
                              void* d_out, int out_size, void* d_ws, size_t ws_size,
                              hipStream_t stream) {
  const float* obs  = (const float*)d_in[0];
  const float* lemb = (const float*)d_in[1];
  const float* w1   = (const float*)d_in[2];
  const float* b1   = (const float*)d_in[3];
  const float* w2   = (const float*)d_in[4];
  const float* b2   = (const float*)d_in[5];
  const float* wr   = (const float*)d_in[6];
  const float* br   = (const float*)d_in[7];
  const float* wm   = (const float*)d_in[8];
  const float* bm   = (const float*)d_in[9];
  const float* wl   = (const float*)d_in[10];
  const float* bl   = (const float*)d_in[11];
  float* out = (float*)d_out;
  _Float16* ws = (_Float16*)d_ws;

  hipLaunchKernelGGL(prep_weights, dim3((WS_TOTAL + 255) / 256), dim3(256), 0, stream,
                     w1, w2, wr, wm, wl, ws);
  hipLaunchKernelGGL(actor_fused, dim3(BATCH / TB), dim3(256), 0, stream,
                     obs, lemb, (const _Float16*)ws, b1, b2, br, bm, bl, out);
}

// Round 5
// 307.285 us; speedup vs baseline: 1.9053x; 1.1439x over previous
//
#include <hip/hip_runtime.h>

#define BATCH 65536
#define TB 64

typedef _Float16 half8 __attribute__((ext_vector_type(8)));
typedef _Float16 half2v __attribute__((ext_vector_type(2)));
typedef float fx4 __attribute__((ext_vector_type(4)));

// workspace layout (in halves)
#define PW1_OFF 0        // [5][256][32]  phi_w1, K padded 146->160
#define PW2_OFF 40960    // [8][256][32]  phi_w2
#define PWR_OFF 106496   // [8][256][32]  rho_w1
#define PWH_OFF 172032   // [8][16][32]   [mean_w | lstd_w | zero-pad] N padded 8->16
#define WS_TOTAL 176128

__global__ __launch_bounds__(256) void prep_weights(
    const float* __restrict__ w1, const float* __restrict__ w2,
    const float* __restrict__ wr, const float* __restrict__ wm,
    const float* __restrict__ wl, _Float16* __restrict__ ws)
{
  int idx = blockIdx.x * 256 + threadIdx.x;
  if (idx < 40960) {
    int kk = idx & 31, n = (idx >> 5) & 255, kt = idx >> 13;
    int k = kt * 32 + kk;
    ws[idx] = (k < 146) ? (_Float16)w1[k * 256 + n] : (_Float16)0.f;
  } else if (idx < 106496) {
    int t = idx - 40960;
    int kk = t & 31, n = (t >> 5) & 255, kt = t >> 13;
    ws[idx] = (_Float16)w2[(kt * 32 + kk) * 256 + n];
  } else if (idx < 172032) {
    int t = idx - 106496;
    int kk = t & 31, n = (t >> 5) & 255, kt = t >> 13;
    ws[idx] = (_Float16)wr[(kt * 32 + kk) * 256 + n];
  } else if (idx < WS_TOTAL) {
    int t = idx - 172032;
    int kk = t & 31, n = (t >> 5) & 15, kt = t >> 9;
    int k = kt * 32 + kk;
    _Float16 v = (_Float16)0.f;
    if (n < 4) v = (_Float16)wm[k * 4 + n];
    else if (n < 8) v = (_Float16)wl[k * 4 + (n - 4)];
    ws[PWH_OFF + t] = v;
  }
}

// fragment-major LDS index: element (row, col) of a 64 x (KT*32) tile.
// a-fragment read for (m, kt, q, l16) is lane-contiguous 16B -> conflict-free ds_read_b128.
__device__ __forceinline__ int afidx(int KT, int row, int col) {
  return ((((row >> 4) * KT + (col >> 5)) * 4 + ((col >> 3) & 3)) * 16 + (row & 15)) * 8 + (col & 7);
}

// R1-R4 post-mortem: any __launch_bounds__ min-waves clamp makes the allocator
// split the unified file into equal arch/accum halves (VGPR_Count pinned at
// budget/2) and spill the arch-side overflow to scratch (~160-400 MB/dispatch
// round-trip = the entire runtime). No min-waves bound: cap 512, expected use
// ~200 total -> still 2 waves/SIMD occupancy, but zero spill.
__global__ __launch_bounds__(256) void actor_fused(
    const float* __restrict__ obs, const float* __restrict__ lemb,
    const _Float16* __restrict__ ws,
    const float* __restrict__ b1, const float* __restrict__ b2,
    const float* __restrict__ br, const float* __restrict__ bm,
    const float* __restrict__ bl, float* __restrict__ out)
{
  __shared__ __align__(16) _Float16 As[TB * 160]; // 20 KB, frag-major, KT=5
  __shared__ __align__(16) _Float16 Hs[TB * 256]; // 32 KB, frag-major, KT=8
  __shared__ _Float16 Fs[TB * 45];                // 5.6 KB object features

  const _Float16* __restrict__ pw1 = ws + PW1_OFF;
  const _Float16* __restrict__ pw2 = ws + PW2_OFF;
  const _Float16* __restrict__ pwr = ws + PWR_OFF;
  const _Float16* __restrict__ pwh = ws + PWH_OFF;

  const int tid = threadIdx.x;
  const int wave = tid >> 6;
  const int lane = tid & 63;
  const int q = lane >> 4;
  const int l16 = lane & 15;
  const int colbase = wave * 64;
  const int rowbase = blockIdx.x * TB;

  // ---- one-time staging: l_emb -> cols 0..99, body -> 100..109, feats -> Fs ----
  for (int idx = tid; idx < TB * 100; idx += 256) {
    int r = idx / 100, c = idx - r * 100;
    As[afidx(5, r, c)] = (_Float16)lemb[(rowbase + r) * 100 + c];
  }
  for (int idx = tid; idx < TB * 55; idx += 256) {
    int r = idx / 55, c = idx - r * 55;
    float v = obs[(rowbase + r) * 55 + c];
    if (c < 10) As[afidx(5, r, 100 + c)] = (_Float16)v;
    else Fs[r * 45 + (c - 10)] = (_Float16)v;
  }
  for (int idx = tid; idx < TB * 14; idx += 256) {
    int r = idx / 14, c = idx - r * 14;
    As[afidx(5, r, 146 + c)] = (_Float16)0.f;
  }

  const fx4 zero4 = {0.f, 0.f, 0.f, 0.f};
  // agg as packed f16: slot (m*4+jn) holds rows (m*16+q*4+rr), col (colbase+jn*16+l16);
  // pair index rp = rr>>1, element rr&1.
  half2v agg2[32];
  #pragma unroll
  for (int i = 0; i < 32; ++i) agg2[i] = (half2v)0;

  for (int p = 0; p < 6; ++p) {
    const int oi = p >> 1;
    const int oj = (1161 >> (2 * p)) & 3; // {1,2,0,2,0,1}

    // ---- build object cols 110..145 from Fs ----
    for (int idx = tid; idx < TB * 36; idx += 256) {
      int r = idx / 36, c = idx - r * 36;
      _Float16 v;
      if (c < 3)       v = (_Float16)((c == oi) ? 1.f : 0.f);
      else if (c < 18) v = Fs[r * 45 + oi * 15 + (c - 3)];
      else if (c < 21) v = (_Float16)(((c - 18) == oj) ? 1.f : 0.f);
      else             v = Fs[r * 45 + oj * 15 + (c - 21)];
      As[afidx(5, r, 110 + c)] = v;
    }
    __syncthreads();

    // ---- GEMM1: h1 = relu(A @ W1 + b1), K=160, N in two 32-col halves ----
    #pragma unroll
    for (int half = 0; half < 2; ++half) {
      fx4 acc[8];
      #pragma unroll
      for (int i = 0; i < 8; ++i) acc[i] = zero4;
      for (int kt = 0; kt < 5; ++kt) {
        half8 a[4], b[2];
        #pragma unroll
        for (int m = 0; m < 4; ++m)
          a[m] = *(const half8*)&As[(((m * 5 + kt) * 4 + q) * 16 + l16) * 8];
        #pragma unroll
        for (int n = 0; n < 2; ++n)
          b[n] = *(const half8*)&pw1[(kt * 256 + colbase + half * 32 + n * 16 + l16) * 32 + q * 8];
        #pragma unroll
        for (int m = 0; m < 4; ++m)
          #pragma unroll
          for (int n = 0; n < 2; ++n)
            acc[m * 2 + n] = __builtin_amdgcn_mfma_f32_16x16x32_f16(a[m], b[n], acc[m * 2 + n], 0, 0, 0);
      }
      #pragma unroll
      for (int n = 0; n < 2; ++n) {
        int col = colbase + half * 32 + n * 16 + l16;
        float bias = b1[col];
        int ktc = col >> 5;            // = wave*2 + half
        int q2 = 2 * n + (l16 >> 3);
        int j = l16 & 7;
        #pragma unroll
        for (int m = 0; m < 4; ++m)
          #pragma unroll
          for (int rr = 0; rr < 4; ++rr) {
            float h = acc[m * 2 + n][rr] + bias;
            Hs[(((m * 8 + ktc) * 4 + q2) * 16 + (4 * q + rr)) * 8 + j] = (_Float16)(h > 0.f ? h : 0.f);
          }
      }
    }
    __syncthreads();

    // ---- GEMM2: agg += relu(h1 @ W2 + b2), K=256, N in halves ----
    #pragma unroll
    for (int half = 0; half < 2; ++half) {
      fx4 acc[8];
      #pragma unroll
      for (int i = 0; i < 8; ++i) acc[i] = zero4;
      for (int kt = 0; kt < 8; ++kt) {
        half8 a[4], b[2];
        #pragma unroll
        for (int m = 0; m < 4; ++m)
          a[m] = *(const half8*)&Hs[(((m * 8 + kt) * 4 + q) * 16 + l16) * 8];
        #pragma unroll
        for (int n = 0; n < 2; ++n)
          b[n] = *(const half8*)&pw2[(kt * 256 + colbase + half * 32 + n * 16 + l16) * 32 + q * 8];
        #pragma unroll
        for (int m = 0; m < 4; ++m)
          #pragma unroll
          for (int n = 0; n < 2; ++n)
            acc[m * 2 + n] = __builtin_amdgcn_mfma_f32_16x16x32_f16(a[m], b[n], acc[m * 2 + n], 0, 0, 0);
      }
      #pragma unroll
      for (int n = 0; n < 2; ++n) {
        int jn = half * 2 + n;
        float bias = b2[colbase + jn * 16 + l16];
        #pragma unroll
        for (int m = 0; m < 4; ++m)
          #pragma unroll
          for (int rp = 0; rp < 2; ++rp) {
            float h0 = acc[m * 2 + n][rp * 2 + 0] + bias;
            float h1 = acc[m * 2 + n][rp * 2 + 1] + bias;
            half2v hv;
            hv[0] = (_Float16)(h0 > 0.f ? h0 : 0.f);
            hv[1] = (_Float16)(h1 > 0.f ? h1 : 0.f);
            agg2[(m * 4 + jn) * 2 + rp] += hv;   // v_pk_add_f16
          }
      }
    }
    __syncthreads();  // Hs reads done before next perm's GEMM1; As build safe
  }

  // ---- stage agg into Hs (already f16) ----
  #pragma unroll
  for (int jn = 0; jn < 4; ++jn) {
    int col = colbase + jn * 16 + l16;
    int ktc = col >> 5;
    int q2 = 2 * (jn & 1) + (l16 >> 3);
    int j = l16 & 7;
    #pragma unroll
    for (int m = 0; m < 4; ++m)
      #pragma unroll
      for (int rr = 0; rr < 4; ++rr)
        Hs[(((m * 8 + ktc) * 4 + q2) * 16 + (4 * q + rr)) * 8 + j] = agg2[(m * 4 + jn) * 2 + (rr >> 1)][rr & 1];
  }
  __syncthreads();

  // ---- GEMM3: r = relu(agg @ rho_w1 + rho_b1), K=256, full N (agg2 dead) ----
  fx4 acc3[16];
  #pragma unroll
  for (int i = 0; i < 16; ++i) acc3[i] = zero4;
  for (int kt = 0; kt < 8; ++kt) {
    half8 a[4], b[4];
    #pragma unroll
    for (int m = 0; m < 4; ++m)
      a[m] = *(const half8*)&Hs[(((m * 8 + kt) * 4 + q) * 16 + l16) * 8];
    #pragma unroll
    for (int n = 0; n < 4; ++n)
      b[n] = *(const half8*)&pwr[(kt * 256 + colbase + n * 16 + l16) * 32 + q * 8];
    #pragma unroll
    for (int m = 0; m < 4; ++m)
      #pragma unroll
      for (int n = 0; n < 4; ++n)
        acc3[m * 4 + n] = __builtin_amdgcn_mfma_f32_16x16x32_f16(a[m], b[n], acc3[m * 4 + n], 0, 0, 0);
  }
  __syncthreads();  // all reads of Hs done before overwrite
  #pragma unroll
  for (int n = 0; n < 4; ++n) {
    int col = colbase + n * 16 + l16;
    float bias = br[col];
    int ktc = col >> 5;
    int q2 = 2 * (n & 1) + (l16 >> 3);
    int j = l16 & 7;
    #pragma unroll
    for (int m = 0; m < 4; ++m)
      #pragma unroll
      for (int rr = 0; rr < 4; ++rr) {
        float h = acc3[m * 4 + n][rr] + bias;
        Hs[(((m * 8 + ktc) * 4 + q2) * 16 + (4 * q + rr)) * 8 + j] = (_Float16)(h > 0.f ? h : 0.f);
      }
  }
  __syncthreads();

  // ---- heads: [mean | log_std] = r @ PWh (N padded to 16) ----
  fx4 a4 = zero4;
  for (int kt = 0; kt < 8; ++kt) {
    half8 a = *(const half8*)&Hs[(((wave * 8 + kt) * 4 + q) * 16 + l16) * 8];
    half8 b = *(const half8*)&pwh[(kt * 16 + l16) * 32 + q * 8];
    a4 = __builtin_amdgcn_mfma_f32_16x16x32_f16(a, b, a4, 0, 0, 0);
  }
  int gr = rowbase + wave * 16 + q * 4;
  if (l16 < 4) {
    float bias = bm[l16];
    #pragma unroll
    for (int rr = 0; rr < 4; ++rr) out[(gr + rr) * 4 + l16] = a4[rr] + bias;
  } else if (l16 < 8) {
    int c = l16 - 4;
    float bias = bl[c];
    #pragma unroll
    for (int rr = 0; rr < 4; ++rr) {
      float v = a4[rr] + bias;
      v = v < -20.f ? -20.f : (v > 2.f ? 2.f : v);
      out[BATCH * 4 + (gr + rr) * 4 + c] = v;
    }
  }
}

extern "C" void kernel_launch(void* const* d_in, const int* in_sizes, int n_in,
                              void* d_out, int out_size, void* d_ws, size_t ws_size,
                              hipStream_t stream) {
  const float* obs  = (const float*)d_in[0];
  const float* lemb = (const float*)d_in[1];
  const float* w1   = (const float*)d_in[2];
  const float* b1   = (const float*)d_in[3];
  const float* w2   = (const float*)d_in[4];
  const float* b2   = (const float*)d_in[5];
  const float* wr   = (const float*)d_in[6];
  const float* br   = (const float*)d_in[7];
  const float* wm   = (const float*)d_in[8];
  const float* bm   = (const float*)d_in[9];
  const float* wl   = (const float*)d_in[10];
  const float* bl   = (const float*)d_in[11];
  float* out = (float*)d_out;
  _Float16* ws = (_Float16*)d_ws;

  hipLaunchKernelGGL(prep_weights, dim3((WS_TOTAL + 255) / 256), dim3(256), 0, stream,
                     w1, w2, wr, wm, wl, ws);
  hipLaunchKernelGGL(actor_fused, dim3(BATCH / TB), dim3(256), 0, stream,
                     obs, lemb, (const _Float16*)ws, b1, b2, br, bm, bl, out);
}